// Round 3
// baseline (698.332 us; speedup 1.0000x reference)
//
#include <hip/hip_runtime.h>

// Problem constants (fixed by the reference).
#define NGRID 262144      // N = 64^3 = 2^18
#define NNZ_C 1835008     // 7 * N
#define NBKT  1024        // row buckets
#define BROWS 256         // rows per bucket (NGRID / NBKT)

// ---------------------------------------------------------------------------
// Block reduction for 256-thread blocks (4 waves of 64).
// ---------------------------------------------------------------------------
__device__ __forceinline__ float block_reduce_sum_256(float v) {
    __shared__ float red[4];
    #pragma unroll
    for (int o = 32; o > 0; o >>= 1) v += __shfl_down(v, o);
    const int wave = threadIdx.x >> 6;
    const int lane = threadIdx.x & 63;
    if (lane == 0) red[wave] = v;
    __syncthreads();
    float s = 0.f;
    if (threadIdx.x == 0) {
        #pragma unroll
        for (int i = 0; i < 4; ++i) s += red[i];
    }
    return s;
}

// ===========================================================================
// FAST PATH (bucketed sort, no global atomics)
// ===========================================================================

// K_A: fused transpose yp(32,N)->yp_t(N,32) + per-slice <yt,yp> partials
// p1[blk*32+b]; block 0 also zeroes the global histogram.
// grid = N/64 = 4096 blocks x 256.
__global__ __launch_bounds__(256) void k_prep(
        const float* __restrict__ yp, const float* __restrict__ yt,
        float* __restrict__ yp_t, float* __restrict__ p1,
        int* __restrict__ hist) {
    __shared__ float tile[64 * 33];
    const int tid = threadIdx.x;
    if (blockIdx.x == 0) {
        #pragma unroll
        for (int i = 0; i < 4; ++i) hist[i * 256 + tid] = 0;
    }
    const size_t n0 = (size_t)blockIdx.x * 64;
    const int lane = tid & 63;
    const int w = tid >> 6;
    float acc[8];
    #pragma unroll
    for (int r = 0; r < 8; ++r) {
        const int b = w * 8 + r;
        const float a = yp[(size_t)b * NGRID + n0 + lane];
        const float t = yt[(size_t)b * NGRID + n0 + lane];
        tile[lane * 33 + b] = a;
        acc[r] = a * t;
    }
    __syncthreads();
    #pragma unroll
    for (int q = 0; q < 8; ++q) {
        const int f = q * 256 + tid;
        yp_t[n0 * 32 + f] = tile[(f >> 5) * 33 + (f & 31)];
    }
    #pragma unroll
    for (int r = 0; r < 8; ++r) {
        float v = acc[r];
        #pragma unroll
        for (int o = 32; o > 0; o >>= 1) v += __shfl_down(v, o);
        if (lane == 0) p1[blockIdx.x * 32 + w * 8 + r] = v;
    }
}

// K_B: global histogram of row buckets. grid = 512 x 256, chunk = 3584.
__global__ __launch_bounds__(256) void k_hist(const int* __restrict__ rows,
                                              int* __restrict__ hist) {
    __shared__ int h[NBKT];
    const int tid = threadIdx.x;
    for (int i = tid; i < NBKT; i += 256) h[i] = 0;
    __syncthreads();
    const int chunk = NNZ_C / 512;          // 3584
    const size_t e0 = (size_t)blockIdx.x * chunk;
    for (int i = tid; i < chunk; i += 256) atomicAdd(&h[rows[e0 + i] >> 8], 1);
    __syncthreads();
    for (int i = tid; i < NBKT; i += 256)
        if (h[i]) atomicAdd(&hist[i], h[i]);
}

// K_C: exclusive scan of 1024 counts -> base, cursor. 1 block x 1024.
__global__ __launch_bounds__(1024) void k_scan(const int* __restrict__ hist,
                                               int* __restrict__ base,
                                               int* __restrict__ cursor) {
    __shared__ int s[2][NBKT];
    const int tid = threadIdx.x;
    const int v = hist[tid];
    s[0][tid] = v;
    __syncthreads();
    int p = 0;
    for (int off = 1; off < NBKT; off <<= 1) {
        int t = s[p][tid];
        if (tid >= off) t += s[p][tid - off];
        s[1 ^ p][tid] = t;          // write buffer != read buffer
        __syncthreads();
        p ^= 1;
    }
    const int excl = s[p][tid] - v;
    base[tid] = excl;
    cursor[tid] = excl;
    if (tid == 0) base[NBKT] = NNZ_C;
}

// K_D: reorder edges by bucket. Packs (row&255)<<24 | col (col<2^18) + val.
// grid = 256 x 256, chunk = 7168. Per-block LDS hist -> one global
// reservation per bucket -> LDS-cursor scatter.
__global__ __launch_bounds__(256) void k_reorder(
        const int* __restrict__ rows, const int* __restrict__ cols,
        const float* __restrict__ vals, int* __restrict__ cursor,
        int* __restrict__ rc_out, float* __restrict__ v_out) {
    __shared__ int h[NBKT];
    __shared__ int bl[NBKT];
    const int tid = threadIdx.x;
    for (int i = tid; i < NBKT; i += 256) h[i] = 0;
    __syncthreads();
    const int chunk = NNZ_C / 256;          // 7168
    const size_t e0 = (size_t)blockIdx.x * chunk;
    for (int i = tid; i < chunk; i += 256) atomicAdd(&h[rows[e0 + i] >> 8], 1);
    __syncthreads();
    for (int i = tid; i < NBKT; i += 256) {
        const int c = h[i];
        bl[i] = c ? atomicAdd(&cursor[i], c) : 0;
        h[i] = 0;                           // reuse as intra-block cursor
    }
    __syncthreads();
    for (int i = tid; i < chunk; i += 256) {
        const int r = rows[e0 + i];
        const int bk = r >> 8;
        const int off = atomicAdd(&h[bk], 1);
        const int pos = bl[bk] + off;
        rc_out[pos] = ((r & 255) << 24) | cols[e0 + i];
        v_out[pos] = vals[e0 + i];
    }
}

// K_E: per-bucket accumulate in LDS (ds atomics), coalesced yat_t write,
// fused <yp, A yp> partial (p2[k*32+b]). grid = NBKT x 256.
// acc bank = (rl*32+b)%32 = b -> conflict-free per 32-lane half; 2-way
// across halves is free. Gather yp_t[col*32+b]: one 128B line per edge.
__global__ __launch_bounds__(256) void k_accum(
        const int* __restrict__ rc, const float* __restrict__ vv,
        const int* __restrict__ base, const float* __restrict__ yp_t,
        float* __restrict__ yat_t, float* __restrict__ p2) {
    __shared__ float acc[BROWS * 32];       // 32 KB
    __shared__ float red[256];
    const int tid = threadIdx.x;
    #pragma unroll
    for (int i = 0; i < 32; ++i) acc[i * 256 + tid] = 0.f;
    __syncthreads();
    const int k = blockIdx.x;
    const int start = base[k], end = base[k + 1];
    const int half = tid >> 5;              // 0..7 -> 8 edges per block-iter
    const int b = tid & 31;
    for (int e = start + half; e < end; e += 16) {   // unroll x2 for MLP
        const int e1 = e + 8;
        const bool has1 = (e1 < end);
        const int rc0 = rc[e];
        const float v0 = vv[e];
        int rc1 = 0; float v1 = 0.f;
        if (has1) { rc1 = rc[e1]; v1 = vv[e1]; }
        const float x0 = yp_t[(size_t)(rc0 & 0x3FFFF) * 32 + b];
        float x1 = 0.f;
        if (has1) x1 = yp_t[(size_t)(rc1 & 0x3FFFF) * 32 + b];
        atomicAdd(&acc[(((unsigned)rc0) >> 24) * 32 + b], v0 * x0);
        if (has1) atomicAdd(&acc[(((unsigned)rc1) >> 24) * 32 + b], v1 * x1);
    }
    __syncthreads();
    const size_t o0 = (size_t)k * (BROWS * 32);
    float pa = 0.f;
    #pragma unroll
    for (int i = 0; i < 32; ++i) {
        const int f = i * 256 + tid;        // f&31 == tid&31 == b
        const float a = acc[f];
        pa = fmaf(a, yp_t[o0 + f], pa);
        yat_t[o0 + f] = a;
    }
    red[tid] = pa;
    __syncthreads();
    if (tid < 32) {
        float s = 0.f;
        #pragma unroll
        for (int j = 0; j < 8; ++j) s += red[tid + 32 * j];
        p2[k * 32 + tid] = s;
    }
}

// K_F: alpha[b] = sum(p1[:,b]) / sum(p2[:,b]). 1 block x 256.
__global__ __launch_bounds__(256) void k_alpha2(const float* __restrict__ p1,
                                                const float* __restrict__ p2,
                                                float* __restrict__ alpha) {
    __shared__ float r1[256], r2[256];
    const int tid = threadIdx.x;
    const int b = tid & 31, j = tid >> 5;
    float s1 = 0.f, s2 = 0.f;
    for (int k = j; k < 4096; k += 8) s1 += p1[k * 32 + b];
    for (int k = j; k < NBKT; k += 8) s2 += p2[k * 32 + b];
    r1[tid] = s1; r2[tid] = s2;
    __syncthreads();
    if (tid < 32) {
        float a = 0.f, c = 0.f;
        #pragma unroll
        for (int q = 0; q < 8; ++q) { a += r1[tid + 32 * q]; c += r2[tid + 32 * q]; }
        alpha[tid] = a / c;
    }
}

// ===========================================================================
// Shared epilogue kernels
// ===========================================================================

// K_G: loss partials. grid = N/256 x 256.
__global__ __launch_bounds__(256) void k_loss(
        const float* __restrict__ yt, const float* __restrict__ yat_t,
        const float* __restrict__ alpha, float* __restrict__ p3) {
    __shared__ float tile[256 * 33];
    __shared__ float a_sh[32];
    const int tid = threadIdx.x;
    if (tid < 32) a_sh[tid] = alpha[tid];
    const size_t n0 = (size_t)blockIdx.x * 256;
    #pragma unroll
    for (int w = 0; w < 32; ++w) {
        const int f = w * 256 + tid;
        tile[(f >> 5) * 33 + (f & 31)] = yat_t[n0 * 32 + f];
    }
    __syncthreads();
    const int wave = tid >> 6;
    const int lane = tid & 63;
    float acc = 0.f;
    #pragma unroll
    for (int j = 0; j < 8; ++j) {
        const int b = wave * 8 + j;
        const float a = a_sh[b];
        const float* ytr = yt + (size_t)b * NGRID + n0;
        #pragma unroll
        for (int c = 0; c < 4; ++c) {
            const int nl = c * 64 + lane;
            const float t = ytr[nl];
            const float yv = tile[nl * 33 + b];
            const float r = fmaf(-a, yv, t);
            acc = fmaf(r, r, acc);
        }
    }
    const float s = block_reduce_sum_256(acc);
    if (tid == 0) p3[blockIdx.x] = s;
}

// K_H: final reduce; mean over batch = sum / 32.
__global__ __launch_bounds__(256) void k_final(const float* __restrict__ p3,
                                               float* __restrict__ out) {
    float acc = 0.f;
    for (int i = threadIdx.x; i < 1024; i += 256) acc += p3[i];
    const float s = block_reduce_sum_256(acc);
    if (threadIdx.x == 0) out[0] = s * (1.0f / 32.0f);
}

// ===========================================================================
// FALLBACK PATH (R2 pipeline, global atomics) — used only if ws too small
// ===========================================================================
__global__ void k_transpose_zero(const float* __restrict__ yp,
                                 float* __restrict__ yp_t,
                                 float* __restrict__ yat_t) {
    __shared__ float tile[64 * 33];
    const int tid = threadIdx.x;
    const size_t n0 = (size_t)blockIdx.x * 64;
    const int lane_n = tid & 63;
    const int bq = tid >> 6;
    #pragma unroll
    for (int r = 0; r < 8; ++r) {
        const int b = bq * 8 + r;
        tile[lane_n * 33 + b] = yp[(size_t)b * NGRID + n0 + lane_n];
    }
    __syncthreads();
    #pragma unroll
    for (int w = 0; w < 8; ++w) {
        const int f = w * 256 + tid;
        yp_t[n0 * 32 + f] = tile[(f >> 5) * 33 + (f & 31)];
        yat_t[n0 * 32 + f] = 0.f;
    }
}

__global__ void k_scatter(const float* __restrict__ vals,
                          const int* __restrict__ rows,
                          const int* __restrict__ cols,
                          const float* __restrict__ yp_t,
                          float* __restrict__ yat_t) {
    const size_t tid = (size_t)blockIdx.x * blockDim.x + threadIdx.x;
    const int b = (int)(tid & 31);
    const size_t e = tid >> 5;
    const float v = vals[e];
    const int r = rows[e];
    const int c = cols[e];
    const float x = yp_t[(size_t)c * 32 + b];
    atomicAdd(&yat_t[(size_t)r * 32 + b], v * x);
}

__global__ void k_dot_yty(const float* __restrict__ yt,
                          const float* __restrict__ yp,
                          float* __restrict__ p1) {
    const int b = blockIdx.y;
    const float4* yt4 = (const float4*)(yt + (size_t)b * NGRID);
    const float4* yp4 = (const float4*)(yp + (size_t)b * NGRID);
    float acc = 0.f;
    for (int i = blockIdx.x * 256 + threadIdx.x; i < NGRID / 4; i += 64 * 256) {
        const float4 a = yt4[i];
        const float4 c = yp4[i];
        acc = fmaf(a.x, c.x, acc);
        acc = fmaf(a.y, c.y, acc);
        acc = fmaf(a.z, c.z, acc);
        acc = fmaf(a.w, c.w, acc);
    }
    const float s = block_reduce_sum_256(acc);
    if (threadIdx.x == 0) p1[b * 64 + blockIdx.x] = s;
}

__global__ void k_dot_yyat(const float* __restrict__ yp_t,
                           const float* __restrict__ yat_t,
                           float* __restrict__ p2) {
    __shared__ float lds[1024];
    float acc[4] = {0.f, 0.f, 0.f, 0.f};
    const float4* a4 = (const float4*)yp_t;
    const float4* b4 = (const float4*)yat_t;
    for (int i = blockIdx.x * 256 + threadIdx.x; i < (NGRID * 32) / 4; i += 256 * 256) {
        const float4 a = a4[i];
        const float4 b = b4[i];
        acc[0] = fmaf(a.x, b.x, acc[0]);
        acc[1] = fmaf(a.y, b.y, acc[1]);
        acc[2] = fmaf(a.z, b.z, acc[2]);
        acc[3] = fmaf(a.w, b.w, acc[3]);
    }
    #pragma unroll
    for (int j = 0; j < 4; ++j) lds[threadIdx.x * 4 + j] = acc[j];
    __syncthreads();
    if (threadIdx.x < 32) {
        float s = 0.f;
        for (int k = 0; k < 32; ++k) s += lds[threadIdx.x + 32 * k];
        p2[blockIdx.x * 32 + threadIdx.x] = s;
    }
}

__global__ void k_alpha_old(const float* __restrict__ p1,
                            const float* __restrict__ p2,
                            float* __restrict__ alpha) {
    const int b = threadIdx.x;
    float s1 = 0.f, s2 = 0.f;
    for (int j = 0; j < 64; ++j) s1 += p1[b * 64 + j];
    for (int k = 0; k < 256; ++k) s2 += p2[k * 32 + b];
    alpha[b] = s1 / s2;
}

// ===========================================================================
extern "C" void kernel_launch(void* const* d_in, const int* in_sizes, int n_in,
                              void* d_out, int out_size, void* d_ws, size_t ws_size,
                              hipStream_t stream) {
    const float* yp = (const float*)d_in[0];   // y_pred (32, N)
    const float* yt = (const float*)d_in[1];   // y_true (32, N)
    const float* Av = (const float*)d_in[2];   // A_vals (NNZ)
    const int*   Ar = (const int*)d_in[3];     // A_rows (NNZ)
    const int*   Ac = (const int*)d_in[4];     // A_cols (NNZ)
    float* out = (float*)d_out;

    // Fast-path workspace layout (4-byte elements):
    float* ws     = (float*)d_ws;
    float* yp_t   = ws;                                   // N*32   = 8,388,608
    float* yat_t  = yp_t + (size_t)NGRID * 32;            // N*32   = 8,388,608
    int*   rc     = (int*)(yat_t + (size_t)NGRID * 32);   // NNZ
    float* vv     = (float*)(rc + NNZ_C);                 // NNZ
    int*   hist   = (int*)(vv + NNZ_C);                   // 1024
    int*   basep  = hist + NBKT;                          // 1025
    int*   cursor = basep + NBKT + 1;                     // 1024
    float* p1     = (float*)(cursor + NBKT);              // 4096*32 = 131072
    float* p2     = p1 + 4096 * 32;                       // 1024*32 = 32768
    float* alpha  = p2 + NBKT * 32;                       // 32
    float* p3     = alpha + 32;                           // 1024
    const size_t need = (size_t)(p3 + 1024 - ws) * sizeof(float);

    if (ws_size >= need) {
        // ---- fast path: bucketed sort + LDS accumulation ----
        k_prep<<<NGRID / 64, 256, 0, stream>>>(yp, yt, yp_t, p1, hist);
        k_hist<<<512, 256, 0, stream>>>(Ar, hist);
        k_scan<<<1, 1024, 0, stream>>>(hist, basep, cursor);
        k_reorder<<<256, 256, 0, stream>>>(Ar, Ac, Av, cursor, rc, vv);
        k_accum<<<NBKT, 256, 0, stream>>>(rc, vv, basep, yp_t, yat_t, p2);
        k_alpha2<<<1, 256, 0, stream>>>(p1, p2, alpha);
        k_loss<<<NGRID / 256, 256, 0, stream>>>(yt, yat_t, alpha, p3);
        k_final<<<1, 256, 0, stream>>>(p3, out);
    } else {
        // ---- fallback: R2 pipeline (67.2 MB ws) ----
        float* f_p1    = (float*)(yat_t + (size_t)NGRID * 32);  // 32*64
        float* f_p2    = f_p1 + 32 * 64;                        // 256*32
        float* f_alpha = f_p2 + 256 * 32;                       // 32
        float* f_p3    = f_alpha + 32;                          // 1024
        k_transpose_zero<<<NGRID / 64, 256, 0, stream>>>(yp, yp_t, yat_t);
        k_scatter<<<(NNZ_C * 32) / 256, 256, 0, stream>>>(Av, Ar, Ac, yp_t, yat_t);
        k_dot_yty<<<dim3(64, 32), 256, 0, stream>>>(yt, yp, f_p1);
        k_dot_yyat<<<256, 256, 0, stream>>>(yp_t, yat_t, f_p2);
        k_alpha_old<<<1, 32, 0, stream>>>(f_p1, f_p2, f_alpha);
        k_loss<<<NGRID / 256, 256, 0, stream>>>(yt, yat_t, f_alpha, f_p3);
        k_final<<<1, 256, 0, stream>>>(f_p3, out);
    }
}

// Round 4
// 551.410 us; speedup vs baseline: 1.2664x; 1.2664x over previous
//
#include <hip/hip_runtime.h>

// Problem constants (fixed by the reference).
#define NGRID 262144      // N = 64^3 = 2^18
#define NNZ_C 1835008     // 7 * N

// Loss closed form:  loss = mean_b( Stt[b] - 2*a[b]*C2[b] + a[b]^2*C3[b] ),
//   a[b] = Sty[b]/C1[b];  C1=<yp,yat>  C2=<yt,yat>  C3=<yat,yat>
//   Stt=<yt,yt>  Sty=<yt,yp>   (all per-batch, summed over n)
// S layout (global scalars, atomically accumulated): S[0..31]=C1, [32..63]=C2,
// [64..95]=C3, [96..127]=Stt, [128..159]=Sty.

// ---------------------------------------------------------------------------
// K1: transpose y_pred (32,N) -> yp_t (N,32); zero yat_t; per-slice
// <yt,yp> partials p1[blk*32+b]; block 0 zeroes S.
// grid = N/64 = 4096 blocks x 256. LDS: one 64x33 tile (8.4 KB).
// ---------------------------------------------------------------------------
__global__ __launch_bounds__(256) void k_prep(
        const float* __restrict__ yp, const float* __restrict__ yt,
        float* __restrict__ yp_t, float* __restrict__ yat_t,
        float* __restrict__ p1, float* __restrict__ S) {
    __shared__ float tile[64 * 33];
    const int tid = threadIdx.x;
    if (blockIdx.x == 0 && tid < 160) S[tid] = 0.f;
    const size_t n0 = (size_t)blockIdx.x * 64;
    const int lane = tid & 63;
    const int w = tid >> 6;
    float acc[8];
    #pragma unroll
    for (int r = 0; r < 8; ++r) {
        const int b = w * 8 + r;
        const float a = yp[(size_t)b * NGRID + n0 + lane];
        const float t = yt[(size_t)b * NGRID + n0 + lane];
        tile[lane * 33 + b] = a;
        acc[r] = a * t;
    }
    __syncthreads();
    #pragma unroll
    for (int q = 0; q < 8; ++q) {
        const int f = q * 256 + tid;            // n-major, b-minor
        yp_t[n0 * 32 + f] = tile[(f >> 5) * 33 + (f & 31)];
        yat_t[n0 * 32 + f] = 0.f;
    }
    #pragma unroll
    for (int r = 0; r < 8; ++r) {
        float v = acc[r];
        #pragma unroll
        for (int o = 32; o > 0; o >>= 1) v += __shfl_down(v, o);
        if (lane == 0) p1[blockIdx.x * 32 + w * 8 + r] = v;
    }
}

// ---------------------------------------------------------------------------
// K2: COO scatter (R2's proven kernel). thread -> (edge e=tid>>5, b=tid&31).
// Gather yp_t[c*32+b]: one 128B line per edge; atomicAdd same contiguity.
// grid = NNZ*32/256 = 229376 blocks — max TLP hides random-gather latency.
// ---------------------------------------------------------------------------
__global__ void k_scatter(const float* __restrict__ vals,
                          const int* __restrict__ rows,
                          const int* __restrict__ cols,
                          const float* __restrict__ yp_t,
                          float* __restrict__ yat_t) {
    const size_t tid = (size_t)blockIdx.x * blockDim.x + threadIdx.x;
    const int b = (int)(tid & 31);
    const size_t e = tid >> 5;
    const float v = vals[e];
    const int r = rows[e];
    const int c = cols[e];
    const float x = yp_t[(size_t)c * 32 + b];
    atomicAdd(&yat_t[(size_t)r * 32 + b], v * x);
}

// ---------------------------------------------------------------------------
// K3: single post-pass. grid = N/256 = 1024 blocks x 256.
// Phase A (flat, coalesced): C1 += yp_t*yat, C3 += yat^2 (residue b=tid&31);
//   stash yat in a 256x33-padded tile.
// Phase B (tile): wave w, b=w*8+j; yt read 256B/wave coalesced;
//   C2 += yt*yat, Stt += yt^2; shuffle-reduce per b.
// Also folds 4 p1-chunks into Sty. One atomicAdd per (scalar,b) per block.
// ---------------------------------------------------------------------------
__global__ __launch_bounds__(256) void k_post(
        const float* __restrict__ yat_t, const float* __restrict__ yp_t,
        const float* __restrict__ yt, const float* __restrict__ p1,
        float* __restrict__ S) {
    __shared__ float tile[256 * 33];
    __shared__ float red[2][256];
    __shared__ float redp[128];
    const int tid = threadIdx.x;
    const size_t n0 = (size_t)blockIdx.x * 256;

    // p1 chunk: 4 prep-blocks (4*32 floats) -> 32 sums
    if (tid < 128) redp[tid] = p1[blockIdx.x * 128 + tid];

    float c1 = 0.f, c3 = 0.f;
    #pragma unroll
    for (int i = 0; i < 32; ++i) {
        const int f = i * 256 + tid;            // f&31 == tid&31 == b
        const float a = yat_t[n0 * 32 + f];
        const float p = yp_t[n0 * 32 + f];
        c1 = fmaf(p, a, c1);
        c3 = fmaf(a, a, c3);
        tile[(f >> 5) * 33 + (f & 31)] = a;
    }
    red[0][tid] = c1;
    red[1][tid] = c3;
    __syncthreads();

    // Phase B: C2, Stt via tile + coalesced yt
    const int w = tid >> 6;
    const int lane = tid & 63;
    #pragma unroll
    for (int j = 0; j < 8; ++j) {
        const int b = w * 8 + j;
        const float* ytr = yt + (size_t)b * NGRID + n0;
        float c2 = 0.f, tt = 0.f;
        #pragma unroll
        for (int c = 0; c < 4; ++c) {
            const int nl = c * 64 + lane;
            const float t = ytr[nl];
            const float yv = tile[nl * 33 + b];
            c2 = fmaf(t, yv, c2);
            tt = fmaf(t, t, tt);
        }
        #pragma unroll
        for (int o = 32; o > 0; o >>= 1) {
            c2 += __shfl_down(c2, o);
            tt += __shfl_down(tt, o);
        }
        if (lane == 0) {
            atomicAdd(&S[32 + b], c2);
            atomicAdd(&S[96 + b], tt);
        }
    }

    // Reduce phase-A residues (8 threads per b) and p1 chunk, then atomics.
    if (tid < 32) {
        float s1 = 0.f, s3 = 0.f;
        #pragma unroll
        for (int k = 0; k < 8; ++k) {
            s1 += red[0][tid + 32 * k];
            s3 += red[1][tid + 32 * k];
        }
        float sy = redp[tid] + redp[tid + 32] + redp[tid + 64] + redp[tid + 96];
        atomicAdd(&S[0 + tid], s1);
        atomicAdd(&S[64 + tid], s3);
        atomicAdd(&S[128 + tid], sy);
    }
}

// ---------------------------------------------------------------------------
// K4: alpha + closed-form loss from the 160 scalars. 1 block x 64.
// ---------------------------------------------------------------------------
__global__ void k_finish(const float* __restrict__ S, float* __restrict__ out) {
    __shared__ float lb[32];
    const int tid = threadIdx.x;
    if (tid < 32) {
        const float c1 = S[tid];
        const float c2 = S[32 + tid];
        const float c3 = S[64 + tid];
        const float tt = S[96 + tid];
        const float ty = S[128 + tid];
        const float a = ty / c1;
        lb[tid] = fmaf(a * a, c3, fmaf(-2.f * a, c2, tt));
    }
    __syncthreads();
    if (tid == 0) {
        float s = 0.f;
        #pragma unroll
        for (int i = 0; i < 32; ++i) s += lb[i];
        out[0] = s * (1.0f / 32.0f);
    }
}

// ===========================================================================
extern "C" void kernel_launch(void* const* d_in, const int* in_sizes, int n_in,
                              void* d_out, int out_size, void* d_ws, size_t ws_size,
                              hipStream_t stream) {
    const float* yp = (const float*)d_in[0];   // y_pred (32, N)
    const float* yt = (const float*)d_in[1];   // y_true (32, N)
    const float* Av = (const float*)d_in[2];   // A_vals (NNZ)
    const int*   Ar = (const int*)d_in[3];     // A_rows (NNZ)
    const int*   Ac = (const int*)d_in[4];     // A_cols (NNZ)
    float* out = (float*)d_out;

    // Workspace: yp_t + yat_t + p1 + S  =  8.39M + 8.39M + 131K + 160 floats
    // ≈ 67.6 MB (same footprint class as R2, which fit).
    float* ws    = (float*)d_ws;
    float* yp_t  = ws;                              // N*32
    float* yat_t = yp_t + (size_t)NGRID * 32;       // N*32
    float* p1    = yat_t + (size_t)NGRID * 32;      // 4096*32
    float* S     = p1 + 4096 * 32;                  // 160

    k_prep<<<NGRID / 64, 256, 0, stream>>>(yp, yt, yp_t, yat_t, p1, S);
    k_scatter<<<(NNZ_C * 32) / 256, 256, 0, stream>>>(Av, Ar, Ac, yp_t, yat_t);
    k_post<<<NGRID / 256, 256, 0, stream>>>(yat_t, yp_t, yt, p1, S);
    k_finish<<<1, 64, 0, stream>>>(S, out);
}

// Round 6
// 413.943 us; speedup vs baseline: 1.6870x; 1.3321x over previous
//
#include <hip/hip_runtime.h>

// Problem constants (fixed by the reference).
#define NGRID 262144      // N = 64^3 = 2^18
#define NNZ_C 1835008     // 7 * N

// Loss closed form:  loss = mean_b( Stt - 2a*C2 + a^2*C3 ),  a = Sty/C1
//   C1=<yp,yat>  C2=<yt,yat>  C3=<yat,yat>  Stt=<yt,yt>  Sty=<yt,yp>
// p2[block][128]: [0..31]=C1 [32..63]=C2 [64..95]=C3 [96..127]=Stt (per b)
// p1[block][32]:  Sty partials (4096 blocks).  NO atomics outside k_scatter.

// ---------------------------------------------------------------------------
// K1: transpose y_pred (32,N) -> yp_t (N,32); zero yat_t; per-slice
// <yt,yp> partials p1[blk*32+b].  (R4's k_prep verbatim, minus S-zeroing.)
// grid = N/64 = 4096 blocks x 256. LDS: one 64x33 tile.
// ---------------------------------------------------------------------------
__global__ __launch_bounds__(256) void k_prep(
        const float* __restrict__ yp, const float* __restrict__ yt,
        float* __restrict__ yp_t, float* __restrict__ yat_t,
        float* __restrict__ p1) {
    __shared__ float tile[64 * 33];
    const int tid = threadIdx.x;
    const size_t n0 = (size_t)blockIdx.x * 64;
    const int lane = tid & 63;
    const int w = tid >> 6;
    float acc[8];
    #pragma unroll
    for (int r = 0; r < 8; ++r) {
        const int b = w * 8 + r;
        const float a = yp[(size_t)b * NGRID + n0 + lane];
        const float t = yt[(size_t)b * NGRID + n0 + lane];
        tile[lane * 33 + b] = a;
        acc[r] = a * t;
    }
    __syncthreads();
    #pragma unroll
    for (int q = 0; q < 8; ++q) {
        const int f = q * 256 + tid;            // n-major, b-minor
        yp_t[n0 * 32 + f] = tile[(f >> 5) * 33 + (f & 31)];
        yat_t[n0 * 32 + f] = 0.f;
    }
    #pragma unroll
    for (int r = 0; r < 8; ++r) {
        float v = acc[r];
        #pragma unroll
        for (int o = 32; o > 0; o >>= 1) v += __shfl_down(v, o);
        if (lane == 0) p1[blockIdx.x * 32 + w * 8 + r] = v;
    }
}

// ---------------------------------------------------------------------------
// K2: COO scatter (proven, untouched). thread -> (e=tid>>5, b=tid&31).
// grid = NNZ*32/256 = 229376 blocks — max TLP hides random-gather latency.
// ---------------------------------------------------------------------------
__global__ void k_scatter(const float* __restrict__ vals,
                          const int* __restrict__ rows,
                          const int* __restrict__ cols,
                          const float* __restrict__ yp_t,
                          float* __restrict__ yat_t) {
    const size_t tid = (size_t)blockIdx.x * blockDim.x + threadIdx.x;
    const int b = (int)(tid & 31);
    const size_t e = tid >> 5;
    const float v = vals[e];
    const int r = rows[e];
    const int c = cols[e];
    const float x = yp_t[(size_t)c * 32 + b];
    atomicAdd(&yat_t[(size_t)r * 32 + b], v * x);
}

// ---------------------------------------------------------------------------
// K3: post-pass (R4's k_post verbatim, except every atomicAdd(&S[slot],v)
// becomes a plain per-block store p2[blk*128+slot]=v; p1-folding removed).
// grid = N/256 = 1024 blocks x 256.
// Phase A (flat, coalesced): C1 += yp_t*yat, C3 += yat^2 (residue b=tid&31);
//   stash yat in a 256x33-padded tile.
// Phase B (tile): wave w, b=w*8+j (unique per (w,j) -> no write collision);
//   yt read 256B/wave coalesced; C2 += yt*yat, Stt += yt^2; shuffle-reduce.
// ---------------------------------------------------------------------------
__global__ __launch_bounds__(256) void k_post(
        const float* __restrict__ yat_t, const float* __restrict__ yp_t,
        const float* __restrict__ yt, float* __restrict__ p2) {
    __shared__ float tile[256 * 33];
    __shared__ float red[2][256];
    const int tid = threadIdx.x;
    const size_t n0 = (size_t)blockIdx.x * 256;

    float c1 = 0.f, c3 = 0.f;
    #pragma unroll
    for (int i = 0; i < 32; ++i) {
        const int f = i * 256 + tid;            // f&31 == tid&31 == b
        const float a = yat_t[n0 * 32 + f];
        const float p = yp_t[n0 * 32 + f];
        c1 = fmaf(p, a, c1);
        c3 = fmaf(a, a, c3);
        tile[(f >> 5) * 33 + (f & 31)] = a;
    }
    red[0][tid] = c1;
    red[1][tid] = c3;
    __syncthreads();

    // Phase B: C2, Stt via tile + coalesced yt. b = w*8+j unique per wave/j.
    const int w = tid >> 6;
    const int lane = tid & 63;
    #pragma unroll
    for (int j = 0; j < 8; ++j) {
        const int b = w * 8 + j;
        const float* ytr = yt + (size_t)b * NGRID + n0;
        float c2 = 0.f, tt = 0.f;
        #pragma unroll
        for (int c = 0; c < 4; ++c) {
            const int nl = c * 64 + lane;
            const float t = ytr[nl];
            const float yv = tile[nl * 33 + b];
            c2 = fmaf(t, yv, c2);
            tt = fmaf(t, t, tt);
        }
        #pragma unroll
        for (int o = 32; o > 0; o >>= 1) {
            c2 += __shfl_down(c2, o);
            tt += __shfl_down(tt, o);
        }
        if (lane == 0) {
            p2[blockIdx.x * 128 + 32 + b] = c2;     // was atomicAdd(&S[32+b])
            p2[blockIdx.x * 128 + 96 + b] = tt;     // was atomicAdd(&S[96+b])
        }
    }

    // Reduce phase-A residues (8 threads per b), then plain stores.
    if (tid < 32) {
        float s1 = 0.f, s3 = 0.f;
        #pragma unroll
        for (int k = 0; k < 8; ++k) {
            s1 += red[0][tid + 32 * k];
            s3 += red[1][tid + 32 * k];
        }
        p2[blockIdx.x * 128 + 0 + tid] = s1;        // was atomicAdd(&S[0+tid])
        p2[blockIdx.x * 128 + 64 + tid] = s3;       // was atomicAdd(&S[64+tid])
    }
}

// ---------------------------------------------------------------------------
// K4: reduce 1024x128 p2 + 4096x32 p1, closed-form loss. 1 block x 256.
// Slot-owner threads, contiguous 512B reads per iteration. ~1.5 MB total.
// ---------------------------------------------------------------------------
__global__ __launch_bounds__(256) void k_finish(
        const float* __restrict__ p2, const float* __restrict__ p1,
        float* __restrict__ out) {
    __shared__ float tot[128];
    __shared__ float styv[32];
    __shared__ float lb[32];
    const int tid = threadIdx.x;
    if (tid < 128) {
        float acc = 0.f;
        for (int j = 0; j < 1024; ++j) acc += p2[(size_t)j * 128 + tid];
        tot[tid] = acc;
    } else if (tid < 160) {
        const int b = tid - 128;
        float acc = 0.f;
        for (int j = 0; j < 4096; ++j) acc += p1[(size_t)j * 32 + b];
        styv[b] = acc;
    }
    __syncthreads();
    if (tid < 32) {
        const float c1 = tot[tid];
        const float c2 = tot[32 + tid];
        const float c3 = tot[64 + tid];
        const float stt = tot[96 + tid];
        const float a = styv[tid] / c1;
        lb[tid] = fmaf(a * a, c3, fmaf(-2.f * a, c2, stt));
    }
    __syncthreads();
    if (tid == 0) {
        float s = 0.f;
        #pragma unroll
        for (int i = 0; i < 32; ++i) s += lb[i];
        out[0] = s * (1.0f / 32.0f);
    }
}

// ===========================================================================
extern "C" void kernel_launch(void* const* d_in, const int* in_sizes, int n_in,
                              void* d_out, int out_size, void* d_ws, size_t ws_size,
                              hipStream_t stream) {
    const float* yp = (const float*)d_in[0];   // y_pred (32, N)
    const float* yt = (const float*)d_in[1];   // y_true (32, N)
    const float* Av = (const float*)d_in[2];   // A_vals (NNZ)
    const int*   Ar = (const int*)d_in[3];     // A_rows (NNZ)
    const int*   Ac = (const int*)d_in[4];     // A_cols (NNZ)
    float* out = (float*)d_out;

    // Workspace: yp_t 32MB + yat_t 32MB + p1 512KB + p2 512KB ≈ 65 MB.
    float* ws    = (float*)d_ws;
    float* yp_t  = ws;                              // N*32
    float* yat_t = yp_t + (size_t)NGRID * 32;       // N*32
    float* p1    = yat_t + (size_t)NGRID * 32;      // 4096*32
    float* p2    = p1 + 4096 * 32;                  // 1024*128

    k_prep<<<NGRID / 64, 256, 0, stream>>>(yp, yt, yp_t, yat_t, p1);
    k_scatter<<<(NNZ_C * 32) / 256, 256, 0, stream>>>(Av, Ar, Ac, yp_t, yat_t);
    k_post<<<NGRID / 256, 256, 0, stream>>>(yat_t, yp_t, yt, p2);
    k_finish<<<1, 256, 0, stream>>>(p2, p1, out);
}

// Round 7
// 348.118 us; speedup vs baseline: 2.0060x; 1.1891x over previous
//
#include <hip/hip_runtime.h>

// Problem constants (fixed by the reference).
#define NGRID 262144      // N = 64^3 = 2^18
#define NNZ_C 1835008     // 7 * N
#define TP    260         // prep LDS row stride (floats); 260*4=1040 ≡ 0 mod 16
                          // -> every row 16B-aligned for ds_write_b128

// Loss closed form:  loss = mean_b( Stt - 2a*C2 + a^2*C3 ),  a = Sty/C1
//   C1=<yp,yat>  C2=<yt,yat>  C3=<yat,yat>  Stt=<yt,yt>  Sty=<yt,yp>
// p2[block][128]: [0..31]=C1 [32..63]=C2 [64..95]=C3 [96..127]=Stt (per b)
// p1[block][32]:  Sty partials (1024 blocks).  NO atomics outside k_scatter.

// ---------------------------------------------------------------------------
// K1: transpose y_pred (32,N) -> yp_t (N,32); zero yat_t; Sty partials.
// grid = N/256 = 1024 blocks x 256.  All global traffic float4:
// Phase 1: wave w, step s -> row b=4s+w, 1 KB contiguous (64 lanes x 16B);
//          stage into T[b][4l..4l+3] (b128, conflict-free); Sty shuffle-sum.
// Phase 2: flat float4 f: elements 4f+k = (n=f>>3, b=4(f&7)+k); gather 4
//          scalars from T (4-way bank alias = 1.58x, cheap), store 1 KB/wave.
// ---------------------------------------------------------------------------
__global__ __launch_bounds__(256) void k_prep(
        const float* __restrict__ yp, const float* __restrict__ yt,
        float* __restrict__ yp_t, float* __restrict__ yat_t,
        float* __restrict__ p1) {
    __shared__ __align__(16) float T[32 * TP];
    __shared__ float p1red[32];
    const int tid = threadIdx.x;
    const int l = tid & 63, w = tid >> 6;
    const size_t n0 = (size_t)blockIdx.x * 256;
    #pragma unroll
    for (int s = 0; s < 8; ++s) {
        const int b = s * 4 + w;                 // unique (s,w) -> 0..31
        const float4 a = *(const float4*)(yp + (size_t)b * NGRID + n0 + 4 * l);
        const float4 t = *(const float4*)(yt + (size_t)b * NGRID + n0 + 4 * l);
        *(float4*)(&T[b * TP + 4 * l]) = a;      // ds_write_b128, row b
        float sty = a.x * t.x + a.y * t.y + a.z * t.z + a.w * t.w;
        #pragma unroll
        for (int o = 32; o > 0; o >>= 1) sty += __shfl_down(sty, o);
        if (l == 0) p1red[b] = sty;
    }
    __syncthreads();
    float4* ypt4 = (float4*)(yp_t + n0 * 32);
    float4* yat4 = (float4*)(yat_t + n0 * 32);
    #pragma unroll
    for (int q = 0; q < 8; ++q) {
        const int f = q * 256 + tid;             // float4 index, 0..2047
        const int n = f >> 3;                    // 0..255 local n
        const int bb = 4 * (f & 7);              // base batch of this quad
        float4 v;
        v.x = T[(bb + 0) * TP + n];
        v.y = T[(bb + 1) * TP + n];
        v.z = T[(bb + 2) * TP + n];
        v.w = T[(bb + 3) * TP + n];
        ypt4[f] = v;                             // coalesced 1 KB/wave
        yat4[f] = make_float4(0.f, 0.f, 0.f, 0.f);
    }
    if (tid < 32) p1[blockIdx.x * 32 + tid] = p1red[tid];
}

// ---------------------------------------------------------------------------
// K2: COO scatter (proven, untouched). thread -> (e=tid>>5, b=tid&31).
// grid = NNZ*32/256 = 229376 blocks — max TLP hides random-gather latency.
// ---------------------------------------------------------------------------
__global__ void k_scatter(const float* __restrict__ vals,
                          const int* __restrict__ rows,
                          const int* __restrict__ cols,
                          const float* __restrict__ yp_t,
                          float* __restrict__ yat_t) {
    const size_t tid = (size_t)blockIdx.x * blockDim.x + threadIdx.x;
    const int b = (int)(tid & 31);
    const size_t e = tid >> 5;
    const float v = vals[e];
    const int r = rows[e];
    const int c = cols[e];
    const float x = yp_t[(size_t)c * 32 + b];
    atomicAdd(&yat_t[(size_t)r * 32 + b], v * x);
}

// ---------------------------------------------------------------------------
// K3: post-pass (R6 verbatim). grid = N/256 = 1024 blocks x 256.
// Per-block partials to p2, no atomics.
// ---------------------------------------------------------------------------
__global__ __launch_bounds__(256) void k_post(
        const float* __restrict__ yat_t, const float* __restrict__ yp_t,
        const float* __restrict__ yt, float* __restrict__ p2) {
    __shared__ float tile[256 * 33];
    __shared__ float red[2][256];
    const int tid = threadIdx.x;
    const size_t n0 = (size_t)blockIdx.x * 256;

    float c1 = 0.f, c3 = 0.f;
    #pragma unroll
    for (int i = 0; i < 32; ++i) {
        const int f = i * 256 + tid;            // f&31 == tid&31 == b
        const float a = yat_t[n0 * 32 + f];
        const float p = yp_t[n0 * 32 + f];
        c1 = fmaf(p, a, c1);
        c3 = fmaf(a, a, c3);
        tile[(f >> 5) * 33 + (f & 31)] = a;
    }
    red[0][tid] = c1;
    red[1][tid] = c3;
    __syncthreads();

    const int w = tid >> 6;
    const int lane = tid & 63;
    #pragma unroll
    for (int j = 0; j < 8; ++j) {
        const int b = w * 8 + j;
        const float* ytr = yt + (size_t)b * NGRID + n0;
        float c2 = 0.f, tt = 0.f;
        #pragma unroll
        for (int c = 0; c < 4; ++c) {
            const int nl = c * 64 + lane;
            const float t = ytr[nl];
            const float yv = tile[nl * 33 + b];
            c2 = fmaf(t, yv, c2);
            tt = fmaf(t, t, tt);
        }
        #pragma unroll
        for (int o = 32; o > 0; o >>= 1) {
            c2 += __shfl_down(c2, o);
            tt += __shfl_down(tt, o);
        }
        if (lane == 0) {
            p2[blockIdx.x * 128 + 32 + b] = c2;
            p2[blockIdx.x * 128 + 96 + b] = tt;
        }
    }

    if (tid < 32) {
        float s1 = 0.f, s3 = 0.f;
        #pragma unroll
        for (int k = 0; k < 8; ++k) {
            s1 += red[0][tid + 32 * k];
            s3 += red[1][tid + 32 * k];
        }
        p2[blockIdx.x * 128 + 0 + tid] = s1;
        p2[blockIdx.x * 128 + 64 + tid] = s3;
    }
}

// ---------------------------------------------------------------------------
// K4: reduce 1024x128 p2 + 1024x32 p1, closed-form loss. 1 block x 256.
// (R6 verbatim except p1 now has 1024 rows.)
// ---------------------------------------------------------------------------
__global__ __launch_bounds__(256) void k_finish(
        const float* __restrict__ p2, const float* __restrict__ p1,
        float* __restrict__ out) {
    __shared__ float tot[128];
    __shared__ float styv[32];
    __shared__ float lb[32];
    const int tid = threadIdx.x;
    if (tid < 128) {
        float acc = 0.f;
        for (int j = 0; j < 1024; ++j) acc += p2[(size_t)j * 128 + tid];
        tot[tid] = acc;
    } else if (tid < 160) {
        const int b = tid - 128;
        float acc = 0.f;
        for (int j = 0; j < 1024; ++j) acc += p1[(size_t)j * 32 + b];
        styv[b] = acc;
    }
    __syncthreads();
    if (tid < 32) {
        const float c1 = tot[tid];
        const float c2 = tot[32 + tid];
        const float c3 = tot[64 + tid];
        const float stt = tot[96 + tid];
        const float a = styv[tid] / c1;
        lb[tid] = fmaf(a * a, c3, fmaf(-2.f * a, c2, stt));
    }
    __syncthreads();
    if (tid == 0) {
        float s = 0.f;
        #pragma unroll
        for (int i = 0; i < 32; ++i) s += lb[i];
        out[0] = s * (1.0f / 32.0f);
    }
}

// ===========================================================================
extern "C" void kernel_launch(void* const* d_in, const int* in_sizes, int n_in,
                              void* d_out, int out_size, void* d_ws, size_t ws_size,
                              hipStream_t stream) {
    const float* yp = (const float*)d_in[0];   // y_pred (32, N)
    const float* yt = (const float*)d_in[1];   // y_true (32, N)
    const float* Av = (const float*)d_in[2];   // A_vals (NNZ)
    const int*   Ar = (const int*)d_in[3];     // A_rows (NNZ)
    const int*   Ac = (const int*)d_in[4];     // A_cols (NNZ)
    float* out = (float*)d_out;

    // Workspace: yp_t 32MB + yat_t 32MB + p1 128KB + p2 512KB ≈ 64.7 MB.
    float* ws    = (float*)d_ws;
    float* yp_t  = ws;                              // N*32
    float* yat_t = yp_t + (size_t)NGRID * 32;       // N*32
    float* p1    = yat_t + (size_t)NGRID * 32;      // 1024*32
    float* p2    = p1 + 1024 * 32;                  // 1024*128

    k_prep<<<NGRID / 256, 256, 0, stream>>>(yp, yt, yp_t, yat_t, p1);
    k_scatter<<<(NNZ_C * 32) / 256, 256, 0, stream>>>(Av, Ar, Ac, yp_t, yat_t);
    k_post<<<NGRID / 256, 256, 0, stream>>>(yat_t, yp_t, yt, p2);
    k_finish<<<1, 256, 0, stream>>>(p2, p1, out);
}